// Round 31
// baseline (46.317 us; speedup 1.0000x reference)
//
#include <hip/hip_runtime.h>

#define NBINS   1024
#define TARGETC 128
#define CAPW    192
#define DET     100
#define XCLIP   4.135166556742356f
#define TOPK    6
#define SCAP    256

typedef float f4 __attribute__((ext_vector_type(4)));

__device__ inline float scalar_to_float(const int* p) {
  int v = *p;
  return (v >= 0 && v < (1 << 20)) ? (float)v : __int_as_float(v);
}

struct Box { float x1, y1, x2, y2; };

__device__ inline Box decode_clip(float4 r, float4 p, float W, float H) {
  float w = p.z - p.x, h = p.w - p.y;
  float cx = p.x + 0.5f * w, cy = p.y + 0.5f * h;
  float dx = r.x / 10.f, dy = r.y / 10.f;
  float dw = fminf(r.z / 5.f, XCLIP), dh = fminf(r.w / 5.f, XCLIP);
  float pcx = dx * w + cx, pcy = dy * h + cy;
  float pw = __expf(dw) * w, ph = __expf(dh) * h;
  Box b;
  b.x1 = fminf(fmaxf(pcx - 0.5f * pw, 0.f), W);
  b.y1 = fminf(fmaxf(pcy - 0.5f * ph, 0.f), H);
  b.x2 = fminf(fmaxf(pcx + 0.5f * pw, 0.f), W);
  b.y2 = fminf(fmaxf(pcy + 0.5f * ph, 0.f), H);
  return b;
}

// K1 v14: thread-per-row gather with INLINE-ASM loads. 24 named f4 outputs
// stay live simultaneously -> allocator cannot recycle (R29: VGPR=36, loads
// batched 4-6 deep, 1.4 TB/s). Volatile asm order + one vmcnt(0) +
// sched_barrier(0) fence. ~280 KB/CU in flight at 12 waves/CU.
__global__ __launch_bounds__(256, 1) void k1_score(
    const float* __restrict__ logits, const float* __restrict__ reg,
    const float* __restrict__ prop, const int* __restrict__ ph,
    const int* __restrict__ pw, unsigned long long* __restrict__ buckets,
    int N) {
  __shared__ unsigned long long candS[SCAP];
  __shared__ int candN;
  const int t = threadIdx.x;
  if (t == 0) candN = 0;
  candS[t] = 0ULL;
  __syncthreads();
  const float W = scalar_to_float(pw), H = scalar_to_float(ph);
  const int row = blockIdx.x * 256 + t;
  if (row < N) {
    float mv0 = -3.402823466e38f, mv1 = -3.402823466e38f;
    int   mi0 = 1 << 20,          mi1 = 1 << 20;
    float e0 = 0.f, e1 = 0.f;
    if (row < N - 1) {
      const size_t a = (size_t)row * 91;
      const float* b4 = logits + (a & ~(size_t)3);
      const int shift = (int)(a & 3);
      f4 R0, R1, R2, R3, R4, R5, R6, R7, R8, R9, R10, R11,
         R12, R13, R14, R15, R16, R17, R18, R19, R20, R21, R22, R23;
#define GLD(Rv, OFF) \
      asm volatile("global_load_dwordx4 %0, %1, off offset:" OFF \
                   : "=v"(Rv) : "v"(b4))
      GLD(R0, "0");    GLD(R1, "16");   GLD(R2, "32");   GLD(R3, "48");
      GLD(R4, "64");   GLD(R5, "80");   GLD(R6, "96");   GLD(R7, "112");
      GLD(R8, "128");  GLD(R9, "144");  GLD(R10, "160"); GLD(R11, "176");
      GLD(R12, "192"); GLD(R13, "208"); GLD(R14, "224"); GLD(R15, "240");
      GLD(R16, "256"); GLD(R17, "272"); GLD(R18, "288"); GLD(R19, "304");
      GLD(R20, "320"); GLD(R21, "336"); GLD(R22, "352"); GLD(R23, "368");
#undef GLD
      asm volatile("s_waitcnt vmcnt(0)" ::: "memory");
      __builtin_amdgcn_sched_barrier(0);
#define PROC(Rv, J)                                                     \
      { int idx = 4 * (J) + 0 - shift; bool ok = (idx >= 0) & (idx < 91); \
        float ex = __expf(Rv[0]); e0 += ok ? ex : 0.f;                  \
        if (ok && Rv[0] > mv0) { mv0 = Rv[0]; mi0 = idx; } }            \
      { int idx = 4 * (J) + 1 - shift; bool ok = (idx >= 0) & (idx < 91); \
        float ex = __expf(Rv[1]); e1 += ok ? ex : 0.f;                  \
        if (ok && Rv[1] > mv1) { mv1 = Rv[1]; mi1 = idx; } }            \
      { int idx = 4 * (J) + 2 - shift; bool ok = (idx >= 0) & (idx < 91); \
        float ex = __expf(Rv[2]); e0 += ok ? ex : 0.f;                  \
        if (ok && Rv[2] > mv0) { mv0 = Rv[2]; mi0 = idx; } }            \
      { int idx = 4 * (J) + 3 - shift; bool ok = (idx >= 0) & (idx < 91); \
        float ex = __expf(Rv[3]); e1 += ok ? ex : 0.f;                  \
        if (ok && Rv[3] > mv1) { mv1 = Rv[3]; mi1 = idx; } }
      PROC(R0, 0)   PROC(R1, 1)   PROC(R2, 2)   PROC(R3, 3)
      PROC(R4, 4)   PROC(R5, 5)   PROC(R6, 6)   PROC(R7, 7)
      PROC(R8, 8)   PROC(R9, 9)   PROC(R10, 10) PROC(R11, 11)
      PROC(R12, 12) PROC(R13, 13) PROC(R14, 14) PROC(R15, 15)
      PROC(R16, 16) PROC(R17, 17) PROC(R18, 18) PROC(R19, 19)
      PROC(R20, 20) PROC(R21, 21) PROC(R22, 22) PROC(R23, 23)
#undef PROC
    } else {
      const float* rp = logits + (size_t)row * 91;
      for (int j = 0; j < 91; ++j) {
        float v = rp[j];
        float ex = __expf(v);
        if (j & 1) { e1 += ex; if (v > mv1) { mv1 = v; mi1 = j; } }
        else       { e0 += ex; if (v > mv0) { mv0 = v; mi0 = j; } }
      }
    }
    float mv = mv0; int mi = mi0;
    if (mv1 > mv || (mv1 == mv && mi1 < mi)) { mv = mv1; mi = mi1; }
    float top1 = __expf(mv) / (e0 + e1);
    float4 rg = ((const float4*)reg)[row];
    float4 pp = ((const float4*)prop)[row];
    Box b = decode_clip(rg, pp, W, H);
    bool valid = (top1 > 0.05f) && ((b.x2 - b.x1) >= 0.01f) && ((b.y2 - b.y1) >= 0.01f);
    if (valid) {
      unsigned int low = ((0x1FFFFFFu - (unsigned int)row) << 7) |
                         (unsigned int)mi;
      unsigned long long key =
          ((unsigned long long)__float_as_uint(top1) << 32) |
          (unsigned long long)low;
      int pos = atomicAdd(&candN, 1);
      if (pos < SCAP) candS[pos] = key;
    }
  }
  __syncthreads();
  const int nc = (candN < SCAP) ? candN : SCAP;
  if (t < TOPK && t >= nc) buckets[(size_t)blockIdx.x * TOPK + t] = 0ULL;
  if (t < nc) {
    unsigned long long my = candS[t];
    int r = 0;
    const int ncr = (nc + 7) & ~7;
    #pragma unroll 8
    for (int j = 0; j < ncr; ++j) r += (candS[j] > my) ? 1 : 0;
    if (r < TOPK) buckets[(size_t)blockIdx.x * TOPK + r] = my;
  }
}

// K2 (R29 tail, unchanged): single block, 1024 threads.
__global__ __launch_bounds__(1024) void k2_tail(
    const unsigned long long* __restrict__ buckets,
    const float* __restrict__ reg, const float* __restrict__ prop,
    const int* __restrict__ ph, const int* __restrict__ pw,
    float* __restrict__ out, int N, int nk2) {
  __shared__ unsigned int lh[4][NBINS];
  __shared__ unsigned long long keys[CAPW];
  __shared__ unsigned int wsum[16];
  __shared__ unsigned int wtail[16];
  __shared__ int bstar;
  __shared__ unsigned int gcnt;
  __shared__ float rx1[CAPW], ry1[CAPW], rx2[CAPW], ry2[CAPW], rsc[CAPW];
  __shared__ int rlab[CAPW];
  __shared__ unsigned int sup[CAPW * 6];
  __shared__ unsigned int colAny[6];
  __shared__ int keepL[DET];
  __shared__ int nkS;
  const int t = threadIdx.x;
  const int lane = t & 63, w = t >> 6;
  const ulonglong2* B2 = (const ulonglong2*)buckets;
  ulonglong2 v8[7];
  #pragma unroll
  for (int i = 0; i < 7; ++i) {
    int j = t + (i << 10);
    if (j < nk2) v8[i] = B2[j];
    else { v8[i].x = 0ULL; v8[i].y = 0ULL; }
  }
  for (int i = t; i < 4 * NBINS; i += 1024) ((unsigned int*)lh)[i] = 0u;
  if (t < CAPW) keys[t] = 0ULL;
  if (t < CAPW * 6 - 1024) sup[t + 1024] = 0u;
  sup[t < CAPW * 6 ? t : 0] = 0u;
  if (t < 6) colAny[t] = 0u;
  if (t == 0) { bstar = 0; gcnt = 0u; nkS = 0; }
  __syncthreads();
  const int sh = t & 3;
  #pragma unroll
  for (int i = 0; i < 7; ++i) {
    if (v8[i].x) {
      float s = __uint_as_float((unsigned int)(v8[i].x >> 32));
      int b = (int)(s * (float)NBINS);
      if (b > NBINS - 1) b = NBINS - 1;
      atomicAdd(&lh[sh][b], 1u);
    }
    if (v8[i].y) {
      float s = __uint_as_float((unsigned int)(v8[i].y >> 32));
      int b = (int)(s * (float)NBINS);
      if (b > NBINS - 1) b = NBINS - 1;
      atomicAdd(&lh[sh][b], 1u);
    }
  }
  __syncthreads();
  const unsigned int h0 = lh[0][t] + lh[1][t] + lh[2][t] + lh[3][t];
  unsigned int v = h0;
  #pragma unroll
  for (int m = 1; m < 64; m <<= 1) {
    unsigned int o = __shfl_down(v, m, 64);
    if (lane + m < 64) v += o;
  }
  if (lane == 0) wsum[w] = v;
  __syncthreads();
  if (w == 0) {
    unsigned int u = (lane < 16) ? wsum[lane] : 0u;
    unsigned int inc = u;
    #pragma unroll
    for (int m = 1; m < 16; m <<= 1) {
      unsigned int o = __shfl_down(inc, m, 64);
      if (lane + m < 16) inc += o;
    }
    if (lane < 16) wtail[lane] = inc - u;
  }
  __syncthreads();
  const unsigned int St = v + wtail[w];
  const unsigned int St1 = St - h0;
  if (St >= TARGETC && St1 < TARGETC) {
    int b = (St > CAPW) ? t + 1 : t;
    if (b > NBINS - 1) b = NBINS - 1;
    bstar = b;
  }
  __syncthreads();
  const int bs = bstar;
  #pragma unroll
  for (int i = 0; i < 7; ++i) {
    #pragma unroll
    for (int e = 0; e < 2; ++e) {
      unsigned long long key = e ? v8[i].y : v8[i].x;
      if (key) {
        float s = __uint_as_float((unsigned int)(key >> 32));
        int b = (int)(s * (float)NBINS);
        if (b > NBINS - 1) b = NBINS - 1;
        if (b >= bs) {
          unsigned int pos = atomicAdd(&gcnt, 1u);
          if (pos < CAPW) keys[pos] = key;
        }
      }
    }
  }
  __syncthreads();
  const int count = (gcnt < (unsigned int)CAPW) ? (int)gcnt : CAPW;
  const float W = scalar_to_float(pw), H = scalar_to_float(ph);
  if (t < CAPW) {
    unsigned long long my = keys[t];
    int r = 0;
    #pragma unroll 8
    for (int j = 0; j < CAPW; ++j) r += (keys[j] > my) ? 1 : 0;
    if (t < count) {
      unsigned int low = (unsigned int)(my & 0xFFFFFFFFULL);
      int lab = (int)(low & 127u);
      int idx = (int)(0x1FFFFFFu - (low >> 7));
      if (idx < 0) idx = 0;
      if (idx > N - 1) idx = N - 1;
      float4 rr = ((const float4*)reg)[idx];
      float4 pp = ((const float4*)prop)[idx];
      Box b = decode_clip(rr, pp, W, H);
      rx1[r] = b.x1; ry1[r] = b.y1; rx2[r] = b.x2; ry2[r] = b.y2;
      rsc[r] = __uint_as_float((unsigned int)(my >> 32));
      rlab[r] = lab;
    } else {
      rlab[t] = -1 - t;
      rx1[t] = 0.f; ry1[t] = 0.f; rx2[t] = 0.f; ry2[t] = 0.f; rsc[t] = 0.f;
    }
  }
  __syncthreads();
  #pragma unroll 4
  for (int p = t; p < (CAPW << 8); p += 1024) {
    int a = p >> 8, b = p & 255;
    if (a < b && b < CAPW && rlab[a] == rlab[b]) {
      float ax = fmaxf(rx1[a], rx1[b]), ay = fmaxf(ry1[a], ry1[b]);
      float bx = fminf(rx2[a], rx2[b]), by = fminf(ry2[a], ry2[b]);
      float iw = fmaxf(bx - ax, 0.f), ih = fmaxf(by - ay, 0.f);
      float inter = iw * ih;
      float a1 = (rx2[a] - rx1[a]) * (ry2[a] - ry1[a]);
      float a2 = (rx2[b] - rx1[b]) * (ry2[b] - ry1[b]);
      if (inter / (a1 + a2 - inter) > 0.5f) {
        atomicOr(&sup[b * 6 + (a >> 5)], 1u << (a & 31));
        atomicOr(&colAny[b >> 5], 1u << (b & 31));
      }
    }
  }
  __syncthreads();
  if (t == 0) {
    unsigned int K0 = 0, K1 = 0, K2 = 0, K3 = 0, K4 = 0, K5 = 0;
    int nk = 0;
#define RESOLVE_WORD(WI, KREG)                                          \
    if (nk < DET && (WI) * 32 < count) {                                \
      unsigned int anyw = colAny[WI];                                   \
      int lim = count - (WI) * 32; if (lim > 32) lim = 32;              \
      for (int b = 0; b < lim; ++b) {                                   \
        if (nk >= DET) break;                                           \
        int p = (WI) * 32 + b;                                          \
        bool keep;                                                      \
        if (!((anyw >> b) & 1u)) {                                      \
          keep = true;                                                  \
        } else {                                                        \
          const unsigned int* col = &sup[p * 6];                        \
          unsigned int hit = (col[0] & K0) | (col[1] & K1) |            \
                             (col[2] & K2) | (col[3] & K3) |            \
                             (col[4] & K4) | (col[5] & K5);             \
          keep = (hit == 0u);                                           \
        }                                                               \
        if (keep) { keepL[nk++] = p; KREG |= (1u << b); }               \
      }                                                                 \
    }
    RESOLVE_WORD(0, K0)
    RESOLVE_WORD(1, K1)
    RESOLVE_WORD(2, K2)
    RESOLVE_WORD(3, K3)
    RESOLVE_WORD(4, K4)
    RESOLVE_WORD(5, K5)
#undef RESOLVE_WORD
    nkS = nk;
  }
  __syncthreads();
  if (t < DET) {
    int nk = nkS;
    bool vld = t < nk;
    int p = vld ? keepL[t] : 0;
    out[t * 4 + 0] = vld ? rx1[p] : 0.f;
    out[t * 4 + 1] = vld ? ry1[p] : 0.f;
    out[t * 4 + 2] = vld ? rx2[p] : 0.f;
    out[t * 4 + 3] = vld ? ry2[p] : 0.f;
    out[400 + t] = vld ? rsc[p] : 0.f;
    out[500 + t] = vld ? (float)rlab[p] : -1.f;
  }
}

extern "C" void kernel_launch(void* const* d_in, const int* in_sizes, int n_in,
                              void* d_out, int out_size, void* d_ws, size_t ws_size,
                              hipStream_t stream) {
  const float* logits = (const float*)d_in[0];
  const float* reg    = (const float*)d_in[1];
  const float* prop   = (const float*)d_in[2];
  const int*   ph     = (const int*)d_in[3];
  const int*   pw     = (const int*)d_in[4];
  float* out = (float*)d_out;

  const int N = in_sizes[1] / 4;
  const int grid = (N + 255) / 256;                 // 782
  const int nk2 = (grid * TOPK + 1) / 2;            // ulonglong2 count

  unsigned long long* buckets = (unsigned long long*)d_ws; // grid*TOPK u64

  k1_score<<<grid, 256, 0, stream>>>(logits, reg, prop, ph, pw, buckets, N);
  k2_tail<<<1, 1024, 0, stream>>>(buckets, reg, prop, ph, pw, out, N, nk2);
}

// Round 32
// 44.071 us; speedup vs baseline: 1.0510x; 1.0510x over previous
//
#include <hip/hip_runtime.h>

#define NBINS   1024
#define TARGETC 128
#define CAPW    192
#define DET     100
#define XCLIP   4.135166556742356f
#define CHUNK   48
#define TILE4   1152   // 18 slots x 64 float4 (1092 used + clamp pad)
#define TOPK    3
#define SCAP    64     // per-block staging cap (max rows/block = 48)

__device__ inline float scalar_to_float(const int* p) {
  int v = *p;
  return (v >= 0 && v < (1 << 20)) ? (float)v : __int_as_float(v);
}

struct Box { float x1, y1, x2, y2; };

__device__ inline Box decode_clip(float4 r, float4 p, float W, float H) {
  float w = p.z - p.x, h = p.w - p.y;
  float cx = p.x + 0.5f * w, cy = p.y + 0.5f * h;
  float dx = r.x / 10.f, dy = r.y / 10.f;
  float dw = fminf(r.z / 5.f, XCLIP), dh = fminf(r.w / 5.f, XCLIP);
  float pcx = dx * w + cx, pcy = dy * h + cy;
  float pw = __expf(dw) * w, ph = __expf(dh) * h;
  Box b;
  b.x1 = fminf(fmaxf(pcx - 0.5f * pw, 0.f), W);
  b.y1 = fminf(fmaxf(pcy - 0.5f * ph, 0.f), H);
  b.x2 = fminf(fmaxf(pcx + 0.5f * pw, 0.f), W);
  b.y2 = fminf(fmaxf(pcy + 0.5f * ph, 0.f), H);
  return b;
}

// K1 one-shot (R27/R30 final): each block stages ONE 48-row tile via
// global_load_lds, one barrier, 4-lanes/row compute, candS epilogue ->
// fixed 3-slot slab.
__global__ __launch_bounds__(256) void k1_score(
    const float* __restrict__ logits, const float* __restrict__ reg,
    const float* __restrict__ prop, const int* __restrict__ ph,
    const int* __restrict__ pw, unsigned long long* __restrict__ buckets,
    int N) {
  __shared__ float4 tile[TILE4];             // 18432 B
  __shared__ unsigned long long candS[SCAP]; // 512 B
  __shared__ int candN;
  const int t = threadIdx.x, wv = t >> 6, lane = t & 63;
  if (t == 0) candN = 0;
  if (t < SCAP) candS[t] = 0ULL;
  const float W = scalar_to_float(pw), H = scalar_to_float(ph);
  const int base = blockIdx.x * CHUNK;
  const int rows = (base < N) ? min(CHUNK, N - base) : 0;
  if (rows > 0) {
    const int nf = rows * 91, nf4 = nf >> 2;
    const float4* s4 = (const float4*)(logits + (size_t)base * 91);
    #pragma unroll
    for (int k = 0; k < 5; ++k) {
      int b4 = (wv + (k << 2)) << 6;        // slots wv, wv+4, ..., wv+16
      if (b4 < nf4) {
        int g = b4 + lane;
        if (g > nf4 - 1) g = nf4 - 1;       // clamped dups land in pad slots
        __builtin_amdgcn_global_load_lds(
            (const __attribute__((address_space(1))) void*)(s4 + g),
            (__attribute__((address_space(3))) void*)(&tile[0] + b4),
            16, 0, 0);
      }
    }
    for (int i = (nf4 << 2) + t; i < nf; i += 256)   // partial-last-row tail
      ((float*)tile)[i] = logits[(size_t)base * 91 + i];
  }
  __syncthreads();                          // drains staging; covers candS init
  if (rows > 0) {
    const int r = t >> 2, s = t & 3;
    if (r < rows) {
      const float* rowp = (const float*)tile + r * 91;
      float mv = -3.402823466e38f; int mi = 1 << 20;
      float e0 = 0.f, e1 = 0.f;
      #pragma unroll
      for (int k = 0; k < 23; ++k) {
        int j = s + (k << 2);
        if (j < 91) {
          float v = rowp[j];
          float ex = __expf(v);
          if (k & 1) e1 += ex; else e0 += ex;
          if (v > mv) { mv = v; mi = j; }
        }
      }
      float e = e0 + e1;
      #pragma unroll
      for (int m = 1; m <= 2; m <<= 1) {
        float ov = __shfl_xor(mv, m, 64);
        int   oi = __shfl_xor(mi, m, 64);
        float oe = __shfl_xor(e, m, 64);
        e += oe;
        if (ov > mv || (ov == mv && oi < mi)) { mv = ov; mi = oi; }
      }
      if (s == 0) {
        float top1 = __expf(mv) / e;
        const int row = base + r;
        float4 rg = ((const float4*)reg)[row];
        float4 pp = ((const float4*)prop)[row];
        Box b = decode_clip(rg, pp, W, H);
        bool valid = (top1 > 0.05f) && ((b.x2 - b.x1) >= 0.01f) && ((b.y2 - b.y1) >= 0.01f);
        if (valid) {
          unsigned int low = ((0x1FFFFFFu - (unsigned int)row) << 7) |
                             (unsigned int)mi;
          unsigned long long key =
              ((unsigned long long)__float_as_uint(top1) << 32) |
              (unsigned long long)low;
          int pos = atomicAdd(&candN, 1);
          if (pos < SCAP) candS[pos] = key;
        }
      }
    }
  }
  __syncthreads();
  const int nc = (candN < SCAP) ? candN : SCAP;
  if (t < TOPK && t >= nc) buckets[(size_t)blockIdx.x * TOPK + t] = 0ULL;
  if (t < nc) {
    unsigned long long my = candS[t];
    int r = 0;
    const int ncr = (nc + 7) & ~7;          // <= 48
    #pragma unroll 8
    for (int j = 0; j < ncr; ++j) r += (candS[j] > my) ? 1 : 0;
    if (r < TOPK) buckets[(size_t)blockIdx.x * TOPK + r] = my;
  }
}

// K2 (R27/R30 final): single block, 1024 threads. 7 guarded register rounds
// over the key slab -> 4-sharded hist -> suffix-scan cutoff (128/192) ->
// register compaction -> rank -> 192-bit column suppression matrix ->
// sparse register-mask resolve -> output.
__global__ __launch_bounds__(1024) void k2_tail(
    const unsigned long long* __restrict__ buckets,
    const float* __restrict__ reg, const float* __restrict__ prop,
    const int* __restrict__ ph, const int* __restrict__ pw,
    float* __restrict__ out, int N, int nk2) {
  __shared__ unsigned int lh[4][NBINS];    // sharded hist, 16 KB
  __shared__ unsigned long long keys[CAPW];
  __shared__ unsigned int wsum[16];
  __shared__ unsigned int wtail[16];
  __shared__ int bstar;
  __shared__ unsigned int gcnt;
  __shared__ float rx1[CAPW], ry1[CAPW], rx2[CAPW], ry2[CAPW], rsc[CAPW];
  __shared__ int rlab[CAPW];
  __shared__ unsigned int sup[CAPW * 6];   // column-wise 192-bit masks
  __shared__ unsigned int colAny[6];
  __shared__ int keepL[DET];
  __shared__ int nkS;
  const int t = threadIdx.x;
  const int lane = t & 63, w = t >> 6;
  const ulonglong2* B2 = (const ulonglong2*)buckets;
  ulonglong2 v8[7];
  #pragma unroll
  for (int i = 0; i < 7; ++i) {
    int j = t + (i << 10);
    if (j < nk2) v8[i] = B2[j];
    else { v8[i].x = 0ULL; v8[i].y = 0ULL; }
  }
  for (int i = t; i < 4 * NBINS; i += 1024) ((unsigned int*)lh)[i] = 0u;
  if (t < CAPW) keys[t] = 0ULL;
  if (t < CAPW * 6 - 1024) sup[t + 1024] = 0u;
  sup[t < CAPW * 6 ? t : 0] = 0u;
  if (t < 6) colAny[t] = 0u;
  if (t == 0) { bstar = 0; gcnt = 0u; nkS = 0; }
  __syncthreads();
  const int sh = t & 3;
  #pragma unroll
  for (int i = 0; i < 7; ++i) {
    if (v8[i].x) {
      float s = __uint_as_float((unsigned int)(v8[i].x >> 32));
      int b = (int)(s * (float)NBINS);
      if (b > NBINS - 1) b = NBINS - 1;
      atomicAdd(&lh[sh][b], 1u);
    }
    if (v8[i].y) {
      float s = __uint_as_float((unsigned int)(v8[i].y >> 32));
      int b = (int)(s * (float)NBINS);
      if (b > NBINS - 1) b = NBINS - 1;
      atomicAdd(&lh[sh][b], 1u);
    }
  }
  __syncthreads();
  const unsigned int h0 = lh[0][t] + lh[1][t] + lh[2][t] + lh[3][t];
  unsigned int v = h0;
  #pragma unroll
  for (int m = 1; m < 64; m <<= 1) {
    unsigned int o = __shfl_down(v, m, 64);
    if (lane + m < 64) v += o;
  }
  if (lane == 0) wsum[w] = v;
  __syncthreads();
  if (w == 0) {
    unsigned int u = (lane < 16) ? wsum[lane] : 0u;
    unsigned int inc = u;
    #pragma unroll
    for (int m = 1; m < 16; m <<= 1) {
      unsigned int o = __shfl_down(inc, m, 64);
      if (lane + m < 16) inc += o;
    }
    if (lane < 16) wtail[lane] = inc - u;
  }
  __syncthreads();
  const unsigned int St = v + wtail[w];
  const unsigned int St1 = St - h0;
  if (St >= TARGETC && St1 < TARGETC) {
    int b = (St > CAPW) ? t + 1 : t;
    if (b > NBINS - 1) b = NBINS - 1;
    bstar = b;
  }
  __syncthreads();
  const int bs = bstar;
  #pragma unroll
  for (int i = 0; i < 7; ++i) {
    #pragma unroll
    for (int e = 0; e < 2; ++e) {
      unsigned long long key = e ? v8[i].y : v8[i].x;
      if (key) {
        float s = __uint_as_float((unsigned int)(key >> 32));
        int b = (int)(s * (float)NBINS);
        if (b > NBINS - 1) b = NBINS - 1;
        if (b >= bs) {
          unsigned int pos = atomicAdd(&gcnt, 1u);
          if (pos < CAPW) keys[pos] = key;
        }
      }
    }
  }
  __syncthreads();
  const int count = (gcnt < (unsigned int)CAPW) ? (int)gcnt : CAPW;
  const float W = scalar_to_float(pw), H = scalar_to_float(ph);
  if (t < CAPW) {
    unsigned long long my = keys[t];
    int r = 0;
    #pragma unroll 8
    for (int j = 0; j < CAPW; ++j) r += (keys[j] > my) ? 1 : 0;
    if (t < count) {
      unsigned int low = (unsigned int)(my & 0xFFFFFFFFULL);
      int lab = (int)(low & 127u);
      int idx = (int)(0x1FFFFFFu - (low >> 7));
      if (idx < 0) idx = 0;
      if (idx > N - 1) idx = N - 1;
      float4 rr = ((const float4*)reg)[idx];
      float4 pp = ((const float4*)prop)[idx];
      Box b = decode_clip(rr, pp, W, H);
      rx1[r] = b.x1; ry1[r] = b.y1; rx2[r] = b.x2; ry2[r] = b.y2;
      rsc[r] = __uint_as_float((unsigned int)(my >> 32));
      rlab[r] = lab;
    } else {
      rlab[t] = -1 - t;                    // distinct negatives: never match
      rx1[t] = 0.f; ry1[t] = 0.f; rx2[t] = 0.f; ry2[t] = 0.f; rsc[t] = 0.f;
    }
  }
  __syncthreads();
  #pragma unroll 4
  for (int p = t; p < (CAPW << 8); p += 1024) {
    int a = p >> 8, b = p & 255;
    if (a < b && b < CAPW && rlab[a] == rlab[b]) {
      float ax = fmaxf(rx1[a], rx1[b]), ay = fmaxf(ry1[a], ry1[b]);
      float bx = fminf(rx2[a], rx2[b]), by = fminf(ry2[a], ry2[b]);
      float iw = fmaxf(bx - ax, 0.f), ih = fmaxf(by - ay, 0.f);
      float inter = iw * ih;
      float a1 = (rx2[a] - rx1[a]) * (ry2[a] - ry1[a]);
      float a2 = (rx2[b] - rx1[b]) * (ry2[b] - ry1[b]);
      if (inter / (a1 + a2 - inter) > 0.5f) {
        atomicOr(&sup[b * 6 + (a >> 5)], 1u << (a & 31));
        atomicOr(&colAny[b >> 5], 1u << (b & 31));
      }
    }
  }
  __syncthreads();
  if (t == 0) {
    unsigned int K0 = 0, K1 = 0, K2 = 0, K3 = 0, K4 = 0, K5 = 0;
    int nk = 0;
#define RESOLVE_WORD(WI, KREG)                                          \
    if (nk < DET && (WI) * 32 < count) {                                \
      unsigned int anyw = colAny[WI];                                   \
      int lim = count - (WI) * 32; if (lim > 32) lim = 32;              \
      for (int b = 0; b < lim; ++b) {                                   \
        if (nk >= DET) break;                                           \
        int p = (WI) * 32 + b;                                          \
        bool keep;                                                      \
        if (!((anyw >> b) & 1u)) {                                      \
          keep = true;                                                  \
        } else {                                                        \
          const unsigned int* col = &sup[p * 6];                        \
          unsigned int hit = (col[0] & K0) | (col[1] & K1) |            \
                             (col[2] & K2) | (col[3] & K3) |            \
                             (col[4] & K4) | (col[5] & K5);             \
          keep = (hit == 0u);                                           \
        }                                                               \
        if (keep) { keepL[nk++] = p; KREG |= (1u << b); }               \
      }                                                                 \
    }
    RESOLVE_WORD(0, K0)
    RESOLVE_WORD(1, K1)
    RESOLVE_WORD(2, K2)
    RESOLVE_WORD(3, K3)
    RESOLVE_WORD(4, K4)
    RESOLVE_WORD(5, K5)
#undef RESOLVE_WORD
    nkS = nk;
  }
  __syncthreads();
  if (t < DET) {
    int nk = nkS;
    bool vld = t < nk;
    int p = vld ? keepL[t] : 0;
    out[t * 4 + 0] = vld ? rx1[p] : 0.f;
    out[t * 4 + 1] = vld ? ry1[p] : 0.f;
    out[t * 4 + 2] = vld ? rx2[p] : 0.f;
    out[t * 4 + 3] = vld ? ry2[p] : 0.f;
    out[400 + t] = vld ? rsc[p] : 0.f;
    out[500 + t] = vld ? (float)rlab[p] : -1.f;
  }
}

extern "C" void kernel_launch(void* const* d_in, const int* in_sizes, int n_in,
                              void* d_out, int out_size, void* d_ws, size_t ws_size,
                              hipStream_t stream) {
  const float* logits = (const float*)d_in[0];
  const float* reg    = (const float*)d_in[1];
  const float* prop   = (const float*)d_in[2];
  const int*   ph     = (const int*)d_in[3];
  const int*   pw     = (const int*)d_in[4];
  float* out = (float*)d_out;

  const int N = in_sizes[1] / 4;
  const int grid = (((N + CHUNK - 1) / CHUNK) + 1) & ~1;   // even block count
  const int nk2 = grid * TOPK / 2;                         // ulonglong2 count

  unsigned long long* buckets = (unsigned long long*)d_ws; // grid*TOPK u64

  k1_score<<<grid, 256, 0, stream>>>(logits, reg, prop, ph, pw, buckets, N);
  k2_tail<<<1, 1024, 0, stream>>>(buckets, reg, prop, ph, pw, out, N, nk2);
}